// Round 4
// baseline (315.981 us; speedup 1.0000x reference)
//
#include <hip/hip_runtime.h>

// Fused Conv3d(3->16, 3x3x3, VALID) + bias + channel softmax + maxpool(4,4,4)/4.
// x: [512,3,16,32,32] f32, w: [16,3,3,3,3] f32, b: [16] f32
// out: [512,16,3,7,7] f32
//
// Grid: one block per (n, pd, ph) = 10752 blocks, 128 threads (112 active in
// compute). Thread = one (h,w) conv column x 4 d-positions x 16 channels.
// R3/R4 changes vs R2 (LDS-pipe bound, VALUBusy 67%, 1.57e7 bank conflicts):
//  - weights read DIRECTLY from global with wave-uniform indices -> s_load
//    into SGPRs (scalar pipe), eliminating 324 ds_read_b128/thread.
//  - pool epilogue: shfl_xor w-reduction first, then 1 atomic per 4 lanes
//    (was 16-way same-address LDS atomic serialization).

#define XS_ROW 33  // 32 + 1 pad to break LDS bank stride

__global__ __launch_bounds__(128) void conv_sm_pool(
    const float* __restrict__ x, const float* __restrict__ w,
    const float* __restrict__ b, float* __restrict__ out) {
  __shared__ float xs[3 * 6 * 6 * XS_ROW];          // [cin][ld][lh][lw]
  __shared__ float pool[7 * 16];                    // [pw][c]

  const int tid = threadIdx.x;
  const int blk = blockIdx.x;
  const int n  = blk / 21;
  const int r  = blk % 21;
  const int pd = r / 7;
  const int ph = r % 7;

  // ---- stage input tile: cin 0..2, d 4pd..4pd+5, h 4ph..4ph+5, w 0..31 ----
  const float* xb = x + ((size_t)n * 3 * 16 * 32 * 32)
                      + (size_t)(4 * pd) * 32 * 32 + (size_t)(4 * ph) * 32;
  for (int i = tid; i < 3 * 6 * 6 * 32; i += 128) {
    int lw = i & 31;
    int rest = i >> 5;           // cin*36 + ld*6 + lh
    int lh = rest % 6;
    int rest2 = rest / 6;
    int ld = rest2 % 6;
    int cin = rest2 / 6;
    xs[((cin * 6 + ld) * 6 + lh) * XS_ROW + lw] =
        xb[((cin * 16 + ld) * 32 + lh) * 32 + lw];
  }
  if (tid < 112) pool[tid] = 0.0f;  // softmax probs are > 0
  __syncthreads();

  if (tid < 112) {
    const int dh = tid / 28;     // 0..3  (conv h = 4*ph + dh)
    const int wp = tid % 28;     // 0..27 (conv w)

    float acc[4][16];
#pragma unroll
    for (int c = 0; c < 16; ++c) {
      float bc = b[c];           // uniform -> scalar load
#pragma unroll
      for (int dd = 0; dd < 4; ++dd) acc[dd][c] = bc;
    }

    // runtime cin/kh/kw loops keep per-iteration SGPR pressure bounded
    // (48 uniform weight loads/iter); kr & c unrolled.
    for (int cin = 0; cin < 3; ++cin) {
      for (int kh = 0; kh < 3; ++kh) {
        for (int kw = 0; kw < 3; ++kw) {
          float in[6];
#pragma unroll
          for (int ld = 0; ld < 6; ++ld)
            in[ld] = xs[((cin * 6 + ld) * 6 + (dh + kh)) * XS_ROW + (wp + kw)];
          const float* wt = w + cin * 27 + kh * 3 + kw;  // + c*81 + kr*9
#pragma unroll
          for (int kr = 0; kr < 3; ++kr) {
#pragma unroll
            for (int c = 0; c < 16; ++c) {
              // wave-uniform address -> s_load (scalar pipe, SGPR operand)
              float wv = wt[c * 81 + kr * 9];
#pragma unroll
              for (int dd = 0; dd < 4; ++dd)
                acc[dd][c] = fmaf(in[dd + kr], wv, acc[dd][c]);
            }
          }
        }
      }
    }

    // ---- softmax over 16 channels per dd, then max over dd ----
    float pm[16];
#pragma unroll
    for (int c = 0; c < 16; ++c) pm[c] = 0.0f;
#pragma unroll
    for (int dd = 0; dd < 4; ++dd) {
      float m = acc[dd][0];
#pragma unroll
      for (int c = 1; c < 16; ++c) m = fmaxf(m, acc[dd][c]);
      float s = 0.0f;
#pragma unroll
      for (int c = 0; c < 16; ++c) {
        acc[dd][c] = __expf(acc[dd][c] - m);
        s += acc[dd][c];
      }
      float rs = 1.0f / s;
#pragma unroll
      for (int c = 0; c < 16; ++c) pm[c] = fmaxf(pm[c], acc[dd][c] * rs);
    }

    // ---- pooled max: reduce over 4 w-lanes via shuffle, then LDS atomic ----
    // lane%4 == wp%4 in both waves (28%4==0, 64%4==0), so xor 1/2 stays
    // within the (dh, pw) group of 4 adjacent lanes.
#pragma unroll
    for (int c = 0; c < 16; ++c) {
      pm[c] = fmaxf(pm[c], __shfl_xor(pm[c], 1, 64));
      pm[c] = fmaxf(pm[c], __shfl_xor(pm[c], 2, 64));
    }
    if ((wp & 3) == 0) {
      const int pw = wp >> 2;
#pragma unroll
      for (int c = 0; c < 16; ++c)
        atomicMax(reinterpret_cast<int*>(&pool[pw * 16 + c]),
                  __float_as_int(pm[c]));  // probs > 0: int order == float order
    }
  }
  __syncthreads();

  if (tid < 112) {
    int c = tid / 7, pw = tid % 7;
    out[(((size_t)n * 16 + c) * 3 + pd) * 49 + (size_t)ph * 7 + pw] =
        pool[pw * 16 + c];
  }
}

extern "C" void kernel_launch(void* const* d_in, const int* in_sizes, int n_in,
                              void* d_out, int out_size, void* d_ws, size_t ws_size,
                              hipStream_t stream) {
  const float* x = (const float*)d_in[0];
  const float* w = (const float*)d_in[1];
  const float* b = (const float*)d_in[2];
  float* out = (float*)d_out;
  (void)in_sizes; (void)n_in; (void)out_size; (void)d_ws; (void)ws_size;
  dim3 grid(512 * 3 * 7);
  dim3 block(128);
  hipLaunchKernelGGL(conv_sm_pool, grid, block, 0, stream, x, w, b, out);
}

// Round 5
// 284.661 us; speedup vs baseline: 1.1100x; 1.1100x over previous
//
#include <hip/hip_runtime.h>

// Fused Conv3d(3->16, 3x3x3, VALID) + bias + channel softmax + maxpool(4,4,4)/4.
// x: [512,3,16,32,32] f32, w: [16,3,3,3,3] f32, b: [16] f32
// out: [512,16,3,7,7] f32
//
// R5: R3 was stall-bound, not LDS-bound (dur 236->231 despite removing 324
// ds_read_b128/thread). Suspect: weight s_loads share lgkmcnt with ds_read ->
// s_waitcnt lgkmcnt(0) drains the LDS queue every iteration.
// Fix: weights pre-transposed to d_ws [tap][c] by a 1-block kernel, read as
// per-lane uniform-address global_load_dwordx4 (vmcnt pipe, L1-resident,
// scheduled ahead with fine-grained vmcnt(N)), decoupled from input ds_reads
// (lgkmcnt). Inner kw/kr/c/dd fully unrolled (576 FMA / ~64 other per iter);
// cin,kh stay runtime loops to keep the body inside I$.

#define XS_ROW 33  // 32 + 1 pad to break LDS bank stride

__global__ void wtrans(const float* __restrict__ w, float* __restrict__ wt) {
  for (int t = threadIdx.x; t < 81 * 16; t += 128) {
    int c = t & 15, tap = t >> 4;
    wt[t] = w[c * 81 + tap];  // wt[tap][c], float4-loadable over c
  }
}

__global__ __launch_bounds__(128) void conv_sm_pool(
    const float* __restrict__ x, const float* __restrict__ wt,
    const float* __restrict__ b, float* __restrict__ out) {
  __shared__ float xs[3 * 6 * 6 * XS_ROW];          // [cin][ld][lh][lw]
  __shared__ float pool[7 * 16];                    // [pw][c]

  const int tid = threadIdx.x;
  const int blk = blockIdx.x;
  const int n  = blk / 21;
  const int r  = blk % 21;
  const int pd = r / 7;
  const int ph = r % 7;

  // ---- stage input tile: cin 0..2, d 4pd..4pd+5, h 4ph..4ph+5, w 0..31 ----
  const float* xb = x + ((size_t)n * 3 * 16 * 32 * 32)
                      + (size_t)(4 * pd) * 32 * 32 + (size_t)(4 * ph) * 32;
  for (int i = tid; i < 3 * 6 * 6 * 32; i += 128) {
    int lw = i & 31;
    int rest = i >> 5;           // cin*36 + ld*6 + lh
    int lh = rest % 6;
    int rest2 = rest / 6;
    int ld = rest2 % 6;
    int cin = rest2 / 6;
    xs[((cin * 6 + ld) * 6 + lh) * XS_ROW + lw] =
        xb[((cin * 16 + ld) * 32 + lh) * 32 + lw];
  }
  if (tid < 112) pool[tid] = 0.0f;  // softmax probs are > 0
  __syncthreads();

  if (tid < 112) {
    const int dh = tid / 28;     // 0..3  (conv h = 4*ph + dh)
    const int wp = tid % 28;     // 0..27 (conv w)

    float acc[4][16];
#pragma unroll
    for (int c = 0; c < 16; ++c) {
      float bc = b[c];
#pragma unroll
      for (int dd = 0; dd < 4; ++dd) acc[dd][c] = bc;
    }

    const float4* wt4 = reinterpret_cast<const float4*>(wt);  // [tap][c/4]
    for (int cin = 0; cin < 3; ++cin) {
      for (int kh = 0; kh < 3; ++kh) {
        // one base address; all 18 ds_reads use immediate offsets
        const float* xbase = &xs[(cin * 36 + dh + kh) * XS_ROW + wp];
        float in[3][6];
#pragma unroll
        for (int kw = 0; kw < 3; ++kw)
#pragma unroll
          for (int ld = 0; ld < 6; ++ld)
            in[kw][ld] = xbase[ld * 6 * XS_ROW + kw];

        // weights: uniform-address dwordx4 loads, vmcnt pipe (L1-resident)
        const float4* wbase = wt4 + (cin * 27 + kh * 3) * 4;
#pragma unroll
        for (int kw = 0; kw < 3; ++kw) {
#pragma unroll
          for (int kr = 0; kr < 3; ++kr) {
#pragma unroll
            for (int j = 0; j < 4; ++j) {
              float4 wv = wbase[(kr * 9 + kw) * 4 + j];
#pragma unroll
              for (int dd = 0; dd < 4; ++dd) {
                acc[dd][j * 4 + 0] = fmaf(in[kw][dd + kr], wv.x, acc[dd][j * 4 + 0]);
                acc[dd][j * 4 + 1] = fmaf(in[kw][dd + kr], wv.y, acc[dd][j * 4 + 1]);
                acc[dd][j * 4 + 2] = fmaf(in[kw][dd + kr], wv.z, acc[dd][j * 4 + 2]);
                acc[dd][j * 4 + 3] = fmaf(in[kw][dd + kr], wv.w, acc[dd][j * 4 + 3]);
              }
            }
          }
        }
      }
    }

    // ---- softmax over 16 channels per dd, then max over dd ----
    float pm[16];
#pragma unroll
    for (int c = 0; c < 16; ++c) pm[c] = 0.0f;
#pragma unroll
    for (int dd = 0; dd < 4; ++dd) {
      float m = acc[dd][0];
#pragma unroll
      for (int c = 1; c < 16; ++c) m = fmaxf(m, acc[dd][c]);
      float s = 0.0f;
#pragma unroll
      for (int c = 0; c < 16; ++c) {
        acc[dd][c] = __expf(acc[dd][c] - m);
        s += acc[dd][c];
      }
      float rs = 1.0f / s;
#pragma unroll
      for (int c = 0; c < 16; ++c) pm[c] = fmaxf(pm[c], acc[dd][c] * rs);
    }

    // ---- pooled max: reduce over 4 w-lanes via shuffle, then LDS atomic ----
    // lane%4 == wp%4 in both waves (28%4==0, 64%4==0).
#pragma unroll
    for (int c = 0; c < 16; ++c) {
      pm[c] = fmaxf(pm[c], __shfl_xor(pm[c], 1, 64));
      pm[c] = fmaxf(pm[c], __shfl_xor(pm[c], 2, 64));
    }
    if ((wp & 3) == 0) {
      const int pw = wp >> 2;
#pragma unroll
      for (int c = 0; c < 16; ++c)
        atomicMax(reinterpret_cast<int*>(&pool[pw * 16 + c]),
                  __float_as_int(pm[c]));  // probs > 0: int order == float order
    }
  }
  __syncthreads();

  if (tid < 112) {
    int c = tid / 7, pw = tid % 7;
    out[(((size_t)n * 16 + c) * 3 + pd) * 49 + (size_t)ph * 7 + pw] =
        pool[pw * 16 + c];
  }
}

extern "C" void kernel_launch(void* const* d_in, const int* in_sizes, int n_in,
                              void* d_out, int out_size, void* d_ws, size_t ws_size,
                              hipStream_t stream) {
  const float* x = (const float*)d_in[0];
  const float* w = (const float*)d_in[1];
  const float* b = (const float*)d_in[2];
  float* out = (float*)d_out;
  float* wt = (float*)d_ws;   // 81*16 floats = 5184 B scratch
  (void)in_sizes; (void)n_in; (void)out_size; (void)ws_size;
  hipLaunchKernelGGL(wtrans, dim3(1), dim3(128), 0, stream, w, wt);
  hipLaunchKernelGGL(conv_sm_pool, dim3(512 * 3 * 7), dim3(128), 0, stream,
                     x, wt, b, out);
}